// Round 15
// baseline (2909.578 us; speedup 1.0000x reference)
//
#include <hip/hip_runtime.h>
#include <math.h>

#define B_   32
#define N_   1024
#define C_   4096
#define HC_  2048
#define D_   64
#define NT_  32768           // B*N tokens
#define BKC_ 32              // K-chunk per staging step
#define NCH_ (HC_ / BKC_)    // 64 chunks
#define TAU_ 0.01f           // exact-recompute margin on z0-z1

// Diagnostic repetition counts (bijective rotation per rep; final state
// identical to 1 rep).  REVERT TO 1 AFTER MEASUREMENT.
#define RMK_ 8
#define R45_ 5
#define R6_  40

typedef __attribute__((ext_vector_type(8))) short s16x8;   // 8 bf16
typedef __attribute__((ext_vector_type(4))) float f32x4;

__device__ __forceinline__ float4 ld4(const float* p) {
    return *reinterpret_cast<const float4*>(p);
}
__device__ __forceinline__ unsigned short f2bf(float f) {   // RNE f32->bf16
    unsigned int u = __float_as_uint(f);
    u += 0x7fffu + ((u >> 16) & 1u);
    return (unsigned short)(u >> 16);
}
__device__ __forceinline__ float bf2f(unsigned short s) {
    return __uint_as_float(((unsigned int)s) << 16);
}

// ---------------------------------------------------------------------------
// K0: prep — split w'[k][col] = lnw[k]*w1[k][col] into bf16 hi/lo planes,
// fragment order [chunk 64][ctile 4][lane 64][j 8].
// ---------------------------------------------------------------------------
__global__ __launch_bounds__(64) void k0_prep(
        const float* __restrict__ lnw, const float* __restrict__ w1,
        short* __restrict__ whG, short* __restrict__ wlG) {
    const int lane = threadIdx.x;
    const int c = blockIdx.x >> 2, ct = blockIdx.x & 3;
    s16x8 hv, lv;
#pragma unroll
    for (int j = 0; j < 8; ++j) {
        const int k = c * 32 + (lane >> 4) * 8 + j;
        const int col = ct * 16 + (lane & 15);
        const float v = lnw[k] * w1[(size_t)k * D_ + col];
        const unsigned short h = f2bf(v);
        hv[j] = (short)h;
        lv[j] = (short)f2bf(v - bf2f(h));
    }
    const size_t base = ((size_t)(c * 4 + ct) * 64 + lane) * 8;
    *reinterpret_cast<s16x8*>(whG + base) = hv;
    *reinterpret_cast<s16x8*>(wlG + base) = lv;
}

// ---------------------------------------------------------------------------
// MK1M: merged MFMA GEMM (bf16x3) + LN stats + upper g-accum.  [REP x RMK_]
// ---------------------------------------------------------------------------
__global__ __launch_bounds__(256) void mk1m(
        const float* __restrict__ x, const float* __restrict__ lnw,
        const float* __restrict__ lnb, const short* __restrict__ whG,
        const short* __restrict__ wlG, float* __restrict__ Pp,
        float* __restrict__ muv, float* __restrict__ rsv,
        float* __restrict__ part) {
    __shared__ float smem[8192];       // 32KB union
    __shared__ float sLow[64], qLow[64];
    short* S = reinterpret_cast<short*>(smem);

    const int t = threadIdx.x;
    const int row = t >> 2, fq = t & 3;
    const int lane = t & 63, w = t >> 6;

#pragma unroll 1
    for (int rep = 0; rep < RMK_; ++rep) {
        const int tid = (blockIdx.x + rep * 171) & 511;
        const int T0 = tid * 64;
        __syncthreads();   // protect smem across reps

        // ===================== Phase G =====================================
        f32x4 acc[4];
#pragma unroll
        for (int ct = 0; ct < 4; ++ct)
#pragma unroll
            for (int r = 0; r < 4; ++r) acc[ct][r] = 0.f;
        float sR = 0.f, qR = 0.f;

        float4 xv1, xv2;
        s16x8 bh[4], bl[4], bh2[4], bl2[4];
        {
            const float* rp = x + (size_t)(T0 + row) * C_;
            xv1 = ld4(rp + fq * 8);
            xv2 = ld4(rp + fq * 8 + 4);
            const s16x8* wp = reinterpret_cast<const s16x8*>(whG);
            const s16x8* lp = reinterpret_cast<const s16x8*>(wlG);
#pragma unroll
            for (int ct = 0; ct < 4; ++ct) {
                bh[ct] = wp[(size_t)ct * 64 + lane];
                bl[ct] = lp[(size_t)ct * 64 + lane];
            }
        }

#pragma unroll 1
        for (int c = 0; c < NCH_; ++c) {
            short* H = S + (c & 1) * 4096;
            short* L = H + 2048;
            {
                const int slot = (row >> 4) * 64 + fq * 16 + (row & 15);
                const float xs[8] = {xv1.x, xv1.y, xv1.z, xv1.w,
                                     xv2.x, xv2.y, xv2.z, xv2.w};
                s16x8 hv, lv;
#pragma unroll
                for (int j = 0; j < 8; ++j) {
                    const unsigned short h = f2bf(xs[j]);
                    hv[j] = (short)h;
                    lv[j] = (short)f2bf(xs[j] - bf2f(h));
                }
                *reinterpret_cast<s16x8*>(H + slot * 8) = hv;
                *reinterpret_cast<s16x8*>(L + slot * 8) = lv;
                sR += ((xs[0] + xs[1]) + (xs[2] + xs[3]))
                    + ((xs[4] + xs[5]) + (xs[6] + xs[7]));
#pragma unroll
                for (int j = 0; j < 8; ++j) qR = fmaf(xs[j], xs[j], qR);
            }
            __syncthreads();
            if (c + 1 < NCH_) {
                const float* rp = x + (size_t)(T0 + row) * C_
                                  + (c + 1) * BKC_;
                xv1 = ld4(rp + fq * 8);
                xv2 = ld4(rp + fq * 8 + 4);
                const s16x8* wp = reinterpret_cast<const s16x8*>(whG);
                const s16x8* lp = reinterpret_cast<const s16x8*>(wlG);
#pragma unroll
                for (int ct = 0; ct < 4; ++ct) {
                    bh2[ct] = wp[((size_t)(c + 1) * 4 + ct) * 64 + lane];
                    bl2[ct] = lp[((size_t)(c + 1) * 4 + ct) * 64 + lane];
                }
            }
            const s16x8 Ah = *reinterpret_cast<const s16x8*>(
                H + (w * 64 + lane) * 8);
            const s16x8 Al = *reinterpret_cast<const s16x8*>(
                L + (w * 64 + lane) * 8);
#pragma unroll
            for (int ct = 0; ct < 4; ++ct) {
                acc[ct] = __builtin_amdgcn_mfma_f32_16x16x32_bf16(
                    Ah, bh[ct], acc[ct], 0, 0, 0);
                acc[ct] = __builtin_amdgcn_mfma_f32_16x16x32_bf16(
                    Al, bh[ct], acc[ct], 0, 0, 0);
                acc[ct] = __builtin_amdgcn_mfma_f32_16x16x32_bf16(
                    Ah, bl[ct], acc[ct], 0, 0, 0);
            }
#pragma unroll
            for (int ct = 0; ct < 4; ++ct) {
                bh[ct] = bh2[ct];
                bl[ct] = bl2[ct];
            }
        }
#pragma unroll
        for (int ct = 0; ct < 4; ++ct)
#pragma unroll
            for (int r = 0; r < 4; ++r) {
                const int tok = T0 + w * 16 + (lane >> 4) * 4 + r;
                Pp[(size_t)tok * D_ + ct * 16 + (lane & 15)] = acc[ct][r];
            }
        sR += __shfl_xor(sR, 1); qR += __shfl_xor(qR, 1);
        sR += __shfl_xor(sR, 2); qR += __shfl_xor(qR, 2);
        if (fq == 0) { sLow[row] = sR; qLow[row] = qR; }
        __syncthreads();

        // ===================== Phase U =====================================
        float4 wv[8], bv[8], gacc[8];
#pragma unroll
        for (int m = 0; m < 8; ++m) {
            wv[m] = ld4(lnw + HC_ + (m * 64 + lane) * 4);
            bv[m] = ld4(lnb + HC_ + (m * 64 + lane) * 4);
            gacc[m] = make_float4(0.f, 0.f, 0.f, 0.f);
        }
        for (int i = 0; i < 16; ++i) {
            const int r = w * 16 + i;
            const int tok = T0 + r;
            const float* rowp = x + (size_t)tok * C_ + HC_;
            float4 v[8];
            float s = 0.f, q = 0.f;
#pragma unroll
            for (int m = 0; m < 8; ++m) {
                v[m] = ld4(rowp + (m * 64 + lane) * 4);
                s += (v[m].x + v[m].y) + (v[m].z + v[m].w);
                q = fmaf(v[m].x, v[m].x, fmaf(v[m].y, v[m].y,
                    fmaf(v[m].z, v[m].z, fmaf(v[m].w, v[m].w, q))));
            }
#pragma unroll
            for (int o = 1; o < 64; o <<= 1) {
                s += __shfl_xor(s, o);
                q += __shfl_xor(q, o);
            }
            const float S = s + sLow[r];
            const float Q = q + qLow[r];
            const float mu = S * (1.f / C_);
            const float rs = rsqrtf(Q * (1.f / C_) - mu * mu + 1e-5f);
            if (lane == 0) {
                muv[tok] = mu;
                rsv[tok] = rs;
            }
#pragma unroll
            for (int m = 0; m < 8; ++m) {
                gacc[m].x += (v[m].x - mu) * rs * wv[m].x + bv[m].x;
                gacc[m].y += (v[m].y - mu) * rs * wv[m].y + bv[m].y;
                gacc[m].z += (v[m].z - mu) * rs * wv[m].z + bv[m].z;
                gacc[m].w += (v[m].w - mu) * rs * wv[m].w + bv[m].w;
            }
        }
        float (*sh)[HC_] = reinterpret_cast<float(*)[HC_]>(smem);
        __syncthreads();   // phase-G LDS dead before overwrite
#pragma unroll
        for (int m = 0; m < 8; ++m)
            *reinterpret_cast<float4*>(&sh[w][(m * 64 + lane) * 4]) = gacc[m];
        __syncthreads();
        float* pp = part + (size_t)tid * HC_;
#pragma unroll
        for (int m = 0; m < 8; ++m) {
            const int j = (m * 64 + lane) * 4;
            const float4 a0 = ld4(&sh[0][j]);
            const float4 a1 = ld4(&sh[1][j]);
            const float4 a2 = ld4(&sh[2][j]);
            const float4 a3 = ld4(&sh[3][j]);
            float4 r;
            r.x = (a0.x + a1.x) + (a2.x + a3.x);
            r.y = (a0.y + a1.y) + (a2.y + a3.y);
            r.z = (a0.z + a1.z) + (a2.z + a3.z);
            r.w = (a0.w + a1.w) + (a2.w + a3.w);
            if (w == (m & 3))
                *reinterpret_cast<float4*>(pp + j) = r;
        }
    }
}

// ---------------------------------------------------------------------------
// K2a: fold partial-reduce + partial GEMVs.  grid 264, block 256.
// ---------------------------------------------------------------------------
__global__ __launch_bounds__(256) void k2a_part(
        const float* __restrict__ part, const float* __restrict__ w1,
        const float* __restrict__ lnw, const float* __restrict__ lnb,
        float* __restrict__ gpart, float* __restrict__ Wpart,
        float* __restrict__ Bpart) {
    __shared__ float Gs[256];
    __shared__ float red[512];
    const int t = threadIdx.x;
    const int d = t & 63, s = t >> 6;
    const int blk = blockIdx.x;
    if (blk < 256) {
        const int b = blk >> 3, jq = blk & 7;
        const int j = jq * 256 + t;
        float a = 0.f;
        for (int k = 0; k < 16; ++k)
            a += part[(size_t)(b * 16 + k) * HC_ + j];
        Gs[t] = a;
        __syncthreads();
        float acc = 0.f;
        const int j0 = jq * 256 + s * 64;
        for (int jj = 0; jj < 64; ++jj)
            acc = fmaf(Gs[s * 64 + jj],
                       w1[(size_t)(HC_ + j0 + jj) * D_ + d], acc);
        red[s * 64 + d] = acc;
        __syncthreads();
        if (s == 0)
            gpart[(size_t)blk * 64 + d] =
                red[d] + red[64 + d] + red[128 + d] + red[192 + d];
    } else {
        const int wq = blk - 256;
        const int c0 = wq * 256 + s * 64;
        float a = 0.f, c2 = 0.f;
        for (int c = c0; c < c0 + 64; ++c) {
            const float wvv = w1[(size_t)c * D_ + d];
            a = fmaf(lnw[c], wvv, a);
            c2 = fmaf(lnb[c], wvv, c2);
        }
        red[s * 64 + d] = a;
        red[256 + s * 64 + d] = c2;
        __syncthreads();
        if (s == 0) {
            Wpart[wq * 64 + d] =
                red[d] + red[64 + d] + red[128 + d] + red[192 + d];
            Bpart[wq * 64 + d] = red[256 + d] + red[320 + d]
                               + red[384 + d] + red[448 + d];
        }
    }
}

// ---------------------------------------------------------------------------
// K45: decision (k2b folded) + masked copy + dz store.  [REP x R45_]
// ---------------------------------------------------------------------------
__global__ __launch_bounds__(256) void k45_decide_mask(
        const float* __restrict__ Pp, const float* __restrict__ muv,
        const float* __restrict__ rsv, const float* __restrict__ gpart,
        const float* __restrict__ Wpart, const float* __restrict__ Bpart,
        const float* __restrict__ b1, const float* __restrict__ w2,
        const float* __restrict__ b2, const float* __restrict__ gum,
        const float* __restrict__ x, float* __restrict__ out,
        float* __restrict__ dzv) {
    const int t = threadIdx.x;
    const int lane = t & 63, w = t >> 6;

#pragma unroll 1
    for (int rep = 0; rep < R45_; ++rep) {
        const int vb = (blockIdx.x + rep * 2731) & 8191;
        const int token = vb * 4 + w;
        const int b = token >> 10;

        float W1 = 0.f, Bsv = 0.f, gt = 0.f;
#pragma unroll
        for (int q = 0; q < 8; ++q) {
            W1 += Wpart[q * 64 + lane];
            Bsv += Bpart[q * 64 + lane];
            gt += gpart[(size_t)(b * 8 + q) * 64 + lane];
        }
        gt *= (1.f / N_);

        const float2 gv = *reinterpret_cast<const float2*>(gum + token * 2);
        const float p = Pp[(size_t)token * D_ + lane];
        const float mu = muv[token], rs = rsv[token];
        float h = rs * (p - mu * W1) + Bsv + gt + b1[lane];
        h = 0.5f * h * (1.f + erff(h * 0.70710678118654752f));
        const float2 w2v = *reinterpret_cast<const float2*>(w2 + lane * 2);
        float l0 = h * w2v.x;
        float l1 = h * w2v.y;
#pragma unroll
        for (int o = 1; o < 64; o <<= 1) {
            l0 += __shfl_xor(l0, o);
            l1 += __shfl_xor(l1, o);
        }
        const float z0 = l0 + b2[0] + gv.x;
        const float z1 = l1 + b2[1] + gv.y;
        if (lane == 0) dzv[token] = z0 - z1;

        float4* dst = reinterpret_cast<float4*>(out + (size_t)token * C_);
        if (z0 >= z1) {
            const float4* src =
                reinterpret_cast<const float4*>(x + (size_t)token * C_);
#pragma unroll
            for (int c = 0; c < 16; ++c)
                dst[c * 64 + lane] = src[c * 64 + lane];
        } else {
            const float4 z = make_float4(0.f, 0.f, 0.f, 0.f);
#pragma unroll
            for (int c = 0; c < 16; ++c)
                dst[c * 64 + lane] = z;
        }
    }
}

// ---------------------------------------------------------------------------
// K6: cleanup — exact f32 recompute for |dz| < TAU_, unrolled x16 (MLP~24).
// [REP x R6_]
// ---------------------------------------------------------------------------
__global__ __launch_bounds__(256) void k6_cleanup(
        const float* __restrict__ x, const float* __restrict__ lnw,
        const float* __restrict__ w1, const float* __restrict__ muv,
        const float* __restrict__ rsv, const float* __restrict__ gpart,
        const float* __restrict__ Wpart, const float* __restrict__ Bpart,
        const float* __restrict__ b1, const float* __restrict__ w2,
        const float* __restrict__ b2, const float* __restrict__ gum,
        const float* __restrict__ dzv, float* __restrict__ out) {
    const int t = threadIdx.x;
    const int lane = t & 63, w = t >> 6;

#pragma unroll 1
    for (int rep = 0; rep < R6_; ++rep) {
        const int vb = (blockIdx.x + rep * 3413) & 8191;
        const int token = vb * 4 + w;
        const float dz = dzv[token];
        if (fabsf(dz) < TAU_) {       // wave-uniform
            const float* xr = x + (size_t)token * C_;
            float pa[4] = {0.f, 0.f, 0.f, 0.f};
#pragma unroll 1
            for (int k = 0; k < HC_; k += 16) {
                const float4 xk0 = ld4(xr + k), xk1 = ld4(xr + k + 4);
                const float4 xk2 = ld4(xr + k + 8), xk3 = ld4(xr + k + 12);
                const float4 wk0 = ld4(lnw + k), wk1 = ld4(lnw + k + 4);
                const float4 wk2 = ld4(lnw + k + 8), wk3 = ld4(lnw + k + 12);
                float w1v[16];
#pragma unroll
                for (int j = 0; j < 16; ++j)
                    w1v[j] = w1[(size_t)(k + j) * D_ + lane];
                const float xs[16] = {xk0.x * wk0.x, xk0.y * wk0.y,
                                      xk0.z * wk0.z, xk0.w * wk0.w,
                                      xk1.x * wk1.x, xk1.y * wk1.y,
                                      xk1.z * wk1.z, xk1.w * wk1.w,
                                      xk2.x * wk2.x, xk2.y * wk2.y,
                                      xk2.z * wk2.z, xk2.w * wk2.w,
                                      xk3.x * wk3.x, xk3.y * wk3.y,
                                      xk3.z * wk3.z, xk3.w * wk3.w};
#pragma unroll
                for (int j = 0; j < 16; ++j)
                    pa[j & 3] = fmaf(xs[j], w1v[j], pa[j & 3]);
            }
            const float p = (pa[0] + pa[1]) + (pa[2] + pa[3]);

            const int b = token >> 10;
            float W1 = 0.f, Bsv = 0.f, gt = 0.f;
#pragma unroll
            for (int q = 0; q < 8; ++q) {
                W1 += Wpart[q * 64 + lane];
                Bsv += Bpart[q * 64 + lane];
                gt += gpart[(size_t)(b * 8 + q) * 64 + lane];
            }
            gt *= (1.f / N_);
            const float2 gv =
                *reinterpret_cast<const float2*>(gum + token * 2);
            const float mu = muv[token], rs = rsv[token];
            float h = rs * (p - mu * W1) + Bsv + gt + b1[lane];
            h = 0.5f * h * (1.f + erff(h * 0.70710678118654752f));
            const float2 w2v =
                *reinterpret_cast<const float2*>(w2 + lane * 2);
            float l0 = h * w2v.x;
            float l1 = h * w2v.y;
#pragma unroll
            for (int o = 1; o < 64; o <<= 1) {
                l0 += __shfl_xor(l0, o);
                l1 += __shfl_xor(l1, o);
            }
            const float z0 = l0 + b2[0] + gv.x;
            const float z1 = l1 + b2[1] + gv.y;
            const bool keepNew = (z0 >= z1);
            const bool keepOld = (dz >= 0.f);
            if (keepNew != keepOld) {
                float4* dst =
                    reinterpret_cast<float4*>(out + (size_t)token * C_);
                if (keepNew) {
                    const float4* src = reinterpret_cast<const float4*>(xr);
#pragma unroll
                    for (int c = 0; c < 16; ++c)
                        dst[c * 64 + lane] = src[c * 64 + lane];
                } else {
                    const float4 z = make_float4(0.f, 0.f, 0.f, 0.f);
#pragma unroll
                    for (int c = 0; c < 16; ++c)
                        dst[c * 64 + lane] = z;
                }
            }
        }
    }
}

// ---------------------------------------------------------------------------
extern "C" void kernel_launch(void* const* d_in, const int* in_sizes, int n_in,
                              void* d_out, int out_size, void* d_ws,
                              size_t ws_size, hipStream_t stream) {
    const float* x   = (const float*)d_in[0];
    const float* gum = (const float*)d_in[1];
    const float* lnw = (const float*)d_in[2];
    const float* lnb = (const float*)d_in[3];
    const float* w1  = (const float*)d_in[4];
    const float* b1  = (const float*)d_in[5];
    const float* w2  = (const float*)d_in[6];
    const float* b2  = (const float*)d_in[7];
    float* out = (float*)d_out;

    float* wsf   = (float*)d_ws;
    float* Pp    = wsf;                                   // 32768*64
    float* muv   = Pp + (size_t)NT_ * D_;                 // 32768
    float* rsv   = muv + NT_;                             // 32768
    float* part  = rsv + NT_;                             // 512*2048
    float* gpart = part + (size_t)512 * HC_;              // 256*64
    float* Wpart = gpart + 256 * 64;                      // 8*64
    float* Bpart = Wpart + 8 * 64;                        // 8*64
    float* dzv   = Bpart + 8 * 64;                        // 32768
    short* whG   = (short*)(dzv + NT_);                   // 131072 shorts
    short* wlG   = whG + (size_t)131072;                  // 131072 shorts

    k0_prep<<<256, 64, 0, stream>>>(lnw, w1, whG, wlG);
    mk1m<<<512, 256, 0, stream>>>(x, lnw, lnb, whG, wlG, Pp, muv, rsv, part);
    k2a_part<<<264, 256, 0, stream>>>(part, w1, lnw, lnb,
                                      gpart, Wpart, Bpart);
    k45_decide_mask<<<NT_ / 4, 256, 0, stream>>>(Pp, muv, rsv, gpart,
                                                 Wpart, Bpart, b1, w2, b2,
                                                 gum, x, out, dzv);
    k6_cleanup<<<NT_ / 4, 256, 0, stream>>>(x, lnw, w1, muv, rsv, gpart,
                                            Wpart, Bpart, b1, w2, b2,
                                            gum, dzv, out);
}

// Round 16
// 426.848 us; speedup vs baseline: 6.8164x; 6.8164x over previous
//
#include <hip/hip_runtime.h>
#include <math.h>

#define B_   32
#define N_   1024
#define C_   4096
#define HC_  2048
#define D_   64
#define NT_  32768           // B*N tokens
#define BKC_ 32              // K-chunk per staging step
#define NCH_ (HC_ / BKC_)    // 64 chunks
#define TAU_ 0.01f           // exact-recompute margin on z0-z1

typedef __attribute__((ext_vector_type(8))) short s16x8;   // 8 bf16
typedef __attribute__((ext_vector_type(4))) float f32x4;

__device__ __forceinline__ float4 ld4(const float* p) {
    return *reinterpret_cast<const float4*>(p);
}
__device__ __forceinline__ unsigned short f2bf(float f) {   // RNE f32->bf16
    unsigned int u = __float_as_uint(f);
    u += 0x7fffu + ((u >> 16) & 1u);
    return (unsigned short)(u >> 16);
}
__device__ __forceinline__ float bf2f(unsigned short s) {
    return __uint_as_float(((unsigned int)s) << 16);
}

// ---------------------------------------------------------------------------
// K0: prep — split w'[k][col] = lnw[k]*w1[k][col] into bf16 hi/lo planes,
// fragment order [chunk 64][ctile 4][lane 64][j 8].
// B-frag convention: col = ctile*16 + (lane&15), k = chunk*32 + (lane>>4)*8+j.
// ---------------------------------------------------------------------------
__global__ __launch_bounds__(64) void k0_prep(
        const float* __restrict__ lnw, const float* __restrict__ w1,
        short* __restrict__ whG, short* __restrict__ wlG) {
    const int lane = threadIdx.x;
    const int c = blockIdx.x >> 2, ct = blockIdx.x & 3;
    s16x8 hv, lv;
#pragma unroll
    for (int j = 0; j < 8; ++j) {
        const int k = c * 32 + (lane >> 4) * 8 + j;
        const int col = ct * 16 + (lane & 15);
        const float v = lnw[k] * w1[(size_t)k * D_ + col];
        const unsigned short h = f2bf(v);
        hv[j] = (short)h;
        lv[j] = (short)f2bf(v - bf2f(h));
    }
    const size_t base = ((size_t)(c * 4 + ct) * 64 + lane) * 8;
    *reinterpret_cast<s16x8*>(whG + base) = hv;
    *reinterpret_cast<s16x8*>(wlG + base) = lv;
}

// ---------------------------------------------------------------------------
// MK1M v2: merged MFMA GEMM (bf16x3) + LN stats + upper g-accum.
// grid 512 (M64 tiles), block 256 (4 waves).  WAVE = CTILE: each wave owns
// 16 output cols -> B-frags in 16 VGPRs (cur+next, hi+lo).  A staged in LDS
// (shared by all waves), XOR-swizzled (^= fq<<3 shorts) -> 2-way writes.
// ---------------------------------------------------------------------------
__global__ __launch_bounds__(256) void mk1m(
        const float* __restrict__ x, const float* __restrict__ lnw,
        const float* __restrict__ lnb, const short* __restrict__ whG,
        const short* __restrict__ wlG, float* __restrict__ Pp,
        float* __restrict__ muv, float* __restrict__ rsv,
        float* __restrict__ part) {
    __shared__ float smem[8192];       // 32KB union (G: 16KB shorts; U: sh)
    __shared__ float sLow[64], qLow[64];
    short* S = reinterpret_cast<short*>(smem);

    const int t = threadIdx.x;
    const int tid = blockIdx.x;
    const int T0 = tid * 64;
    const int row = t >> 2, fq = t & 3;          // staging role
    const int lane = t & 63, w = t >> 6;         // mfma role: wave = ctile

    // ===================== Phase G: MFMA GEMM + lower stats ================
    f32x4 acc[4];                                // acc[rg]: rows rg*16+..
#pragma unroll
    for (int rg = 0; rg < 4; ++rg)
#pragma unroll
        for (int r = 0; r < 4; ++r) acc[rg][r] = 0.f;
    float sR = 0.f, qR = 0.f;

    const s16x8* wp = reinterpret_cast<const s16x8*>(whG);
    const s16x8* lp = reinterpret_cast<const s16x8*>(wlG);
    float4 xv1, xv2;
    s16x8 bhC, blC, bhN, blN;
    {   // prologue: chunk 0
        const float* rp = x + (size_t)(T0 + row) * C_;
        xv1 = ld4(rp + fq * 8);
        xv2 = ld4(rp + fq * 8 + 4);
        bhC = wp[(size_t)w * 64 + lane];
        blC = lp[(size_t)w * 64 + lane];
    }

#pragma unroll 1
    for (int c = 0; c < NCH_; ++c) {
        short* H = S + (c & 1) * 4096;
        short* L = H + 2048;
        // ---- stage A (bf16 hi/lo, swizzled fragment order) + f32 stats ----
        {
            const int sidx =
                (((row >> 4) * 64 + fq * 16 + (row & 15)) * 8) ^ (fq << 3);
            const float xs[8] = {xv1.x, xv1.y, xv1.z, xv1.w,
                                 xv2.x, xv2.y, xv2.z, xv2.w};
            s16x8 hv, lv;
#pragma unroll
            for (int j = 0; j < 8; ++j) {
                const unsigned short h = f2bf(xs[j]);
                hv[j] = (short)h;
                lv[j] = (short)f2bf(xs[j] - bf2f(h));
            }
            *reinterpret_cast<s16x8*>(H + sidx) = hv;
            *reinterpret_cast<s16x8*>(L + sidx) = lv;
            sR += ((xs[0] + xs[1]) + (xs[2] + xs[3]))
                + ((xs[4] + xs[5]) + (xs[6] + xs[7]));
#pragma unroll
            for (int j = 0; j < 8; ++j) qR = fmaf(xs[j], xs[j], qR);
        }
        __syncthreads();
        // ---- prefetch chunk c+1 (x regs + this wave's B frags) ----
        if (c + 1 < NCH_) {
            const float* rp = x + (size_t)(T0 + row) * C_ + (c + 1) * BKC_;
            xv1 = ld4(rp + fq * 8);
            xv2 = ld4(rp + fq * 8 + 4);
            bhN = wp[((size_t)(c + 1) * 4 + w) * 64 + lane];
            blN = lp[((size_t)(c + 1) * 4 + w) * 64 + lane];
        }
        // ---- A-frags (all 4 row-groups) x this wave's ctile: 12 MFMA ----
#pragma unroll
        for (int rg = 0; rg < 4; ++rg) {
            const int ridx = ((rg * 64 + lane) * 8) ^ ((lane >> 4) << 3);
            const s16x8 Ah = *reinterpret_cast<const s16x8*>(H + ridx);
            const s16x8 Al = *reinterpret_cast<const s16x8*>(L + ridx);
            acc[rg] = __builtin_amdgcn_mfma_f32_16x16x32_bf16(
                Ah, bhC, acc[rg], 0, 0, 0);
            acc[rg] = __builtin_amdgcn_mfma_f32_16x16x32_bf16(
                Al, bhC, acc[rg], 0, 0, 0);
            acc[rg] = __builtin_amdgcn_mfma_f32_16x16x32_bf16(
                Ah, blC, acc[rg], 0, 0, 0);
        }
        bhC = bhN;
        blC = blN;
    }
    // ---- write P: D layout col=lane&15, row=(lane>>4)*4+reg (m89) ----
#pragma unroll
    for (int rg = 0; rg < 4; ++rg)
#pragma unroll
        for (int r = 0; r < 4; ++r) {
            const int tok = T0 + rg * 16 + (lane >> 4) * 4 + r;
            Pp[(size_t)tok * D_ + w * 16 + (lane & 15)] = acc[rg][r];
        }
    // ---- lower-stats reduce (threads row*4+fq) ----
    sR += __shfl_xor(sR, 1); qR += __shfl_xor(qR, 1);
    sR += __shfl_xor(sR, 2); qR += __shfl_xor(qR, 2);
    if (fq == 0) { sLow[row] = sR; qLow[row] = qR; }
    __syncthreads();

    // ===================== Phase U: upper stats + g-accum ==================
    float4 wv[8], bv[8], gacc[8];
#pragma unroll
    for (int m = 0; m < 8; ++m) {
        wv[m] = ld4(lnw + HC_ + (m * 64 + lane) * 4);
        bv[m] = ld4(lnb + HC_ + (m * 64 + lane) * 4);
        gacc[m] = make_float4(0.f, 0.f, 0.f, 0.f);
    }
    for (int i = 0; i < 16; ++i) {
        const int r = w * 16 + i;
        const int tok = T0 + r;
        const float* rowp = x + (size_t)tok * C_ + HC_;
        float4 v[8];
        float s = 0.f, q = 0.f;
#pragma unroll
        for (int m = 0; m < 8; ++m) {
            v[m] = ld4(rowp + (m * 64 + lane) * 4);
            s += (v[m].x + v[m].y) + (v[m].z + v[m].w);
            q = fmaf(v[m].x, v[m].x, fmaf(v[m].y, v[m].y,
                fmaf(v[m].z, v[m].z, fmaf(v[m].w, v[m].w, q))));
        }
#pragma unroll
        for (int o = 1; o < 64; o <<= 1) {
            s += __shfl_xor(s, o);
            q += __shfl_xor(q, o);
        }
        const float S = s + sLow[r];
        const float Q = q + qLow[r];
        const float mu = S * (1.f / C_);
        const float rs = rsqrtf(Q * (1.f / C_) - mu * mu + 1e-5f);
        if (lane == 0) {
            muv[tok] = mu;
            rsv[tok] = rs;
        }
#pragma unroll
        for (int m = 0; m < 8; ++m) {
            gacc[m].x += (v[m].x - mu) * rs * wv[m].x + bv[m].x;
            gacc[m].y += (v[m].y - mu) * rs * wv[m].y + bv[m].y;
            gacc[m].z += (v[m].z - mu) * rs * wv[m].z + bv[m].z;
            gacc[m].w += (v[m].w - mu) * rs * wv[m].w + bv[m].w;
        }
    }
    float (*sh)[HC_] = reinterpret_cast<float(*)[HC_]>(smem);
    __syncthreads();   // phase-G LDS dead before overwrite
#pragma unroll
    for (int m = 0; m < 8; ++m)
        *reinterpret_cast<float4*>(&sh[w][(m * 64 + lane) * 4]) = gacc[m];
    __syncthreads();
    float* pp = part + (size_t)tid * HC_;
#pragma unroll
    for (int m = 0; m < 8; ++m) {
        const int j = (m * 64 + lane) * 4;
        const float4 a0 = ld4(&sh[0][j]);
        const float4 a1 = ld4(&sh[1][j]);
        const float4 a2 = ld4(&sh[2][j]);
        const float4 a3 = ld4(&sh[3][j]);
        float4 r;
        r.x = (a0.x + a1.x) + (a2.x + a3.x);
        r.y = (a0.y + a1.y) + (a2.y + a3.y);
        r.z = (a0.z + a1.z) + (a2.z + a3.z);
        r.w = (a0.w + a1.w) + (a2.w + a3.w);
        if (w == (m & 3))
            *reinterpret_cast<float4*>(pp + j) = r;
    }
}

// ---------------------------------------------------------------------------
// K2a: fold partial-reduce + partial GEMVs.  grid 264, block 256.
// ---------------------------------------------------------------------------
__global__ __launch_bounds__(256) void k2a_part(
        const float* __restrict__ part, const float* __restrict__ w1,
        const float* __restrict__ lnw, const float* __restrict__ lnb,
        float* __restrict__ gpart, float* __restrict__ Wpart,
        float* __restrict__ Bpart) {
    __shared__ float Gs[256];
    __shared__ float red[512];
    const int t = threadIdx.x;
    const int d = t & 63, s = t >> 6;
    const int blk = blockIdx.x;
    if (blk < 256) {
        const int b = blk >> 3, jq = blk & 7;
        const int j = jq * 256 + t;
        float a = 0.f;
        for (int k = 0; k < 16; ++k)
            a += part[(size_t)(b * 16 + k) * HC_ + j];
        Gs[t] = a;
        __syncthreads();
        float acc = 0.f;
        const int j0 = jq * 256 + s * 64;
        for (int jj = 0; jj < 64; ++jj)
            acc = fmaf(Gs[s * 64 + jj],
                       w1[(size_t)(HC_ + j0 + jj) * D_ + d], acc);
        red[s * 64 + d] = acc;
        __syncthreads();
        if (s == 0)
            gpart[(size_t)blk * 64 + d] =
                red[d] + red[64 + d] + red[128 + d] + red[192 + d];
    } else {
        const int wq = blk - 256;
        const int c0 = wq * 256 + s * 64;
        float a = 0.f, c2 = 0.f;
        for (int c = c0; c < c0 + 64; ++c) {
            const float wvv = w1[(size_t)c * D_ + d];
            a = fmaf(lnw[c], wvv, a);
            c2 = fmaf(lnb[c], wvv, c2);
        }
        red[s * 64 + d] = a;
        red[256 + s * 64 + d] = c2;
        __syncthreads();
        if (s == 0) {
            Wpart[wq * 64 + d] =
                red[d] + red[64 + d] + red[128 + d] + red[192 + d];
            Bpart[wq * 64 + d] = red[256 + d] + red[320 + d]
                               + red[384 + d] + red[448 + d];
        }
    }
}

// ---------------------------------------------------------------------------
// K45: decision (k2b folded) + masked copy + dz store.  One wave per token.
// ---------------------------------------------------------------------------
__global__ __launch_bounds__(256) void k45_decide_mask(
        const float* __restrict__ Pp, const float* __restrict__ muv,
        const float* __restrict__ rsv, const float* __restrict__ gpart,
        const float* __restrict__ Wpart, const float* __restrict__ Bpart,
        const float* __restrict__ b1, const float* __restrict__ w2,
        const float* __restrict__ b2, const float* __restrict__ gum,
        const float* __restrict__ x, float* __restrict__ out,
        float* __restrict__ dzv) {
    const int t = threadIdx.x;
    const int lane = t & 63, w = t >> 6;
    const int token = blockIdx.x * 4 + w;
    const int b = token >> 10;

    float W1 = 0.f, Bsv = 0.f, gt = 0.f;
#pragma unroll
    for (int q = 0; q < 8; ++q) {
        W1 += Wpart[q * 64 + lane];
        Bsv += Bpart[q * 64 + lane];
        gt += gpart[(size_t)(b * 8 + q) * 64 + lane];
    }
    gt *= (1.f / N_);

    const float2 gv = *reinterpret_cast<const float2*>(gum + token * 2);
    const float p = Pp[(size_t)token * D_ + lane];
    const float mu = muv[token], rs = rsv[token];
    float h = rs * (p - mu * W1) + Bsv + gt + b1[lane];
    h = 0.5f * h * (1.f + erff(h * 0.70710678118654752f));   // exact gelu
    const float2 w2v = *reinterpret_cast<const float2*>(w2 + lane * 2);
    float l0 = h * w2v.x;
    float l1 = h * w2v.y;
#pragma unroll
    for (int o = 1; o < 64; o <<= 1) {
        l0 += __shfl_xor(l0, o);
        l1 += __shfl_xor(l1, o);
    }
    const float z0 = l0 + b2[0] + gv.x;
    const float z1 = l1 + b2[1] + gv.y;
    if (lane == 0) dzv[token] = z0 - z1;

    float4* dst = reinterpret_cast<float4*>(out + (size_t)token * C_);
    if (z0 >= z1) {    // keep (argmax ties -> index 0): copy x
        const float4* src =
            reinterpret_cast<const float4*>(x + (size_t)token * C_);
#pragma unroll
        for (int c = 0; c < 16; ++c)
            dst[c * 64 + lane] = src[c * 64 + lane];
    } else {           // drop: write zeros, skip the x read
        const float4 z = make_float4(0.f, 0.f, 0.f, 0.f);
#pragma unroll
        for (int c = 0; c < 16; ++c)
            dst[c * 64 + lane] = z;
    }
}

// ---------------------------------------------------------------------------
// K6: cleanup — exact f32 recompute for |dz| < TAU_, unrolled x16 (MLP~24).
// ---------------------------------------------------------------------------
__global__ __launch_bounds__(256) void k6_cleanup(
        const float* __restrict__ x, const float* __restrict__ lnw,
        const float* __restrict__ w1, const float* __restrict__ muv,
        const float* __restrict__ rsv, const float* __restrict__ gpart,
        const float* __restrict__ Wpart, const float* __restrict__ Bpart,
        const float* __restrict__ b1, const float* __restrict__ w2,
        const float* __restrict__ b2, const float* __restrict__ gum,
        const float* __restrict__ dzv, float* __restrict__ out) {
    const int t = threadIdx.x;
    const int lane = t & 63, w = t >> 6;
    const int token = blockIdx.x * 4 + w;
    const float dz = dzv[token];
    if (fabsf(dz) >= TAU_) return;    // wave-uniform

    const float* xr = x + (size_t)token * C_;
    float pa[4] = {0.f, 0.f, 0.f, 0.f};
#pragma unroll 1
    for (int k = 0; k < HC_; k += 16) {
        const float4 xk0 = ld4(xr + k), xk1 = ld4(xr + k + 4);
        const float4 xk2 = ld4(xr + k + 8), xk3 = ld4(xr + k + 12);
        const float4 wk0 = ld4(lnw + k), wk1 = ld4(lnw + k + 4);
        const float4 wk2 = ld4(lnw + k + 8), wk3 = ld4(lnw + k + 12);
        float w1v[16];
#pragma unroll
        for (int j = 0; j < 16; ++j)
            w1v[j] = w1[(size_t)(k + j) * D_ + lane];
        const float xs[16] = {xk0.x * wk0.x, xk0.y * wk0.y,
                              xk0.z * wk0.z, xk0.w * wk0.w,
                              xk1.x * wk1.x, xk1.y * wk1.y,
                              xk1.z * wk1.z, xk1.w * wk1.w,
                              xk2.x * wk2.x, xk2.y * wk2.y,
                              xk2.z * wk2.z, xk2.w * wk2.w,
                              xk3.x * wk3.x, xk3.y * wk3.y,
                              xk3.z * wk3.z, xk3.w * wk3.w};
#pragma unroll
        for (int j = 0; j < 16; ++j)
            pa[j & 3] = fmaf(xs[j], w1v[j], pa[j & 3]);
    }
    const float p = (pa[0] + pa[1]) + (pa[2] + pa[3]);

    const int b = token >> 10;
    float W1 = 0.f, Bsv = 0.f, gt = 0.f;
#pragma unroll
    for (int q = 0; q < 8; ++q) {
        W1 += Wpart[q * 64 + lane];
        Bsv += Bpart[q * 64 + lane];
        gt += gpart[(size_t)(b * 8 + q) * 64 + lane];
    }
    gt *= (1.f / N_);
    const float2 gv = *reinterpret_cast<const float2*>(gum + token * 2);
    const float mu = muv[token], rs = rsv[token];
    float h = rs * (p - mu * W1) + Bsv + gt + b1[lane];
    h = 0.5f * h * (1.f + erff(h * 0.70710678118654752f));
    const float2 w2v = *reinterpret_cast<const float2*>(w2 + lane * 2);
    float l0 = h * w2v.x;
    float l1 = h * w2v.y;
#pragma unroll
    for (int o = 1; o < 64; o <<= 1) {
        l0 += __shfl_xor(l0, o);
        l1 += __shfl_xor(l1, o);
    }
    const float z0 = l0 + b2[0] + gv.x;
    const float z1 = l1 + b2[1] + gv.y;
    const bool keepNew = (z0 >= z1);
    const bool keepOld = (dz >= 0.f);
    if (keepNew == keepOld) return;

    float4* dst = reinterpret_cast<float4*>(out + (size_t)token * C_);
    if (keepNew) {
        const float4* src = reinterpret_cast<const float4*>(xr);
#pragma unroll
        for (int c = 0; c < 16; ++c)
            dst[c * 64 + lane] = src[c * 64 + lane];
    } else {
        const float4 z = make_float4(0.f, 0.f, 0.f, 0.f);
#pragma unroll
        for (int c = 0; c < 16; ++c)
            dst[c * 64 + lane] = z;
    }
}

// ---------------------------------------------------------------------------
extern "C" void kernel_launch(void* const* d_in, const int* in_sizes, int n_in,
                              void* d_out, int out_size, void* d_ws,
                              size_t ws_size, hipStream_t stream) {
    const float* x   = (const float*)d_in[0];
    const float* gum = (const float*)d_in[1];
    const float* lnw = (const float*)d_in[2];
    const float* lnb = (const float*)d_in[3];
    const float* w1  = (const float*)d_in[4];
    const float* b1  = (const float*)d_in[5];
    const float* w2  = (const float*)d_in[6];
    const float* b2  = (const float*)d_in[7];
    float* out = (float*)d_out;

    float* wsf   = (float*)d_ws;
    float* Pp    = wsf;                                   // 32768*64
    float* muv   = Pp + (size_t)NT_ * D_;                 // 32768
    float* rsv   = muv + NT_;                             // 32768
    float* part  = rsv + NT_;                             // 512*2048
    float* gpart = part + (size_t)512 * HC_;              // 256*64
    float* Wpart = gpart + 256 * 64;                      // 8*64
    float* Bpart = Wpart + 8 * 64;                        // 8*64
    float* dzv   = Bpart + 8 * 64;                        // 32768
    short* whG   = (short*)(dzv + NT_);                   // 131072 shorts
    short* wlG   = whG + (size_t)131072;                  // 131072 shorts

    k0_prep<<<256, 64, 0, stream>>>(lnw, w1, whG, wlG);
    mk1m<<<512, 256, 0, stream>>>(x, lnw, lnb, whG, wlG, Pp, muv, rsv, part);
    k2a_part<<<264, 256, 0, stream>>>(part, w1, lnw, lnb,
                                      gpart, Wpart, Bpart);
    k45_decide_mask<<<NT_ / 4, 256, 0, stream>>>(Pp, muv, rsv, gpart,
                                                 Wpart, Bpart, b1, w2, b2,
                                                 gum, x, out, dzv);
    k6_cleanup<<<NT_ / 4, 256, 0, stream>>>(x, lnw, w1, muv, rsv, gpart,
                                            Wpart, Bpart, b1, w2, b2,
                                            gum, dzv, out);
}

// Round 17
// 388.338 us; speedup vs baseline: 7.4924x; 1.0992x over previous
//
#include <hip/hip_runtime.h>
#include <math.h>

#define B_   32
#define N_   1024
#define C_   4096
#define HC_  2048
#define D_   64
#define NT_  32768           // B*N tokens
#define BKC_ 128             // K-chunk per staging step (deep streaming)
#define NCH_ (HC_ / BKC_)    // 16 chunks
#define TAU_ 0.01f           // exact-recompute margin on z0-z1

typedef __attribute__((ext_vector_type(8))) short s16x8;   // 8 bf16
typedef __attribute__((ext_vector_type(4))) float f32x4;

__device__ __forceinline__ float4 ld4(const float* p) {
    return *reinterpret_cast<const float4*>(p);
}
__device__ __forceinline__ unsigned short f2bf(float f) {   // RNE f32->bf16
    unsigned int u = __float_as_uint(f);
    u += 0x7fffu + ((u >> 16) & 1u);
    return (unsigned short)(u >> 16);
}
__device__ __forceinline__ float bf2f(unsigned short s) {
    return __uint_as_float(((unsigned int)s) << 16);
}

// ---------------------------------------------------------------------------
// K0: prep — split w'[k][col] = lnw[k]*w1[k][col] into bf16 hi/lo planes,
// fragment order [chunk32 64][ctile 4][lane 64][j 8].
// B-frag convention: col = ctile*16 + (lane&15), k = c32*32 + (lane>>4)*8+j.
// ---------------------------------------------------------------------------
__global__ __launch_bounds__(64) void k0_prep(
        const float* __restrict__ lnw, const float* __restrict__ w1,
        short* __restrict__ whG, short* __restrict__ wlG) {
    const int lane = threadIdx.x;
    const int c = blockIdx.x >> 2, ct = blockIdx.x & 3;
    s16x8 hv, lv;
#pragma unroll
    for (int j = 0; j < 8; ++j) {
        const int k = c * 32 + (lane >> 4) * 8 + j;
        const int col = ct * 16 + (lane & 15);
        const float v = lnw[k] * w1[(size_t)k * D_ + col];
        const unsigned short h = f2bf(v);
        hv[j] = (short)h;
        lv[j] = (short)f2bf(v - bf2f(h));
    }
    const size_t base = ((size_t)(c * 4 + ct) * 64 + lane) * 8;
    *reinterpret_cast<s16x8*>(whG + base) = hv;
    *reinterpret_cast<s16x8*>(wlG + base) = lv;
}

// ---------------------------------------------------------------------------
// MK1M v3: deep-streamed MFMA GEMM (bf16x3) + LN stats + upper g-accum.
// grid 512 (M64 tiles), block 256 (4 waves; wave = ctile).
// BKC=128: staging thread (row=t>>2, fq=t&3) loads 8 consecutive b128
// (128 B in flight -> Little's-law fixed), converts to hi/lo bf16, stages
// into [kk 4][rg 4][lane 64][j 8] layout (conflict-free b128 writes/reads).
// LDS: 64 KB dbuf (2 x 2 planes x 16 KB); single barrier per chunk.
// ---------------------------------------------------------------------------
__global__ __launch_bounds__(256) void mk1m(
        const float* __restrict__ x, const float* __restrict__ lnw,
        const float* __restrict__ lnb, const short* __restrict__ whG,
        const short* __restrict__ wlG, float* __restrict__ Pp,
        float* __restrict__ muv, float* __restrict__ rsv,
        float* __restrict__ part) {
    __shared__ short S[32768];         // 64 KB: [buf2][plane2][8192]
    __shared__ float sLow[64], qLow[64];

    const int t = threadIdx.x;
    const int tid = blockIdx.x;
    const int T0 = tid * 64;
    const int row = t >> 2, fq = t & 3;          // staging role
    const int lane = t & 63, w = t >> 6;         // mfma role: wave = ctile
    const int rgS = row >> 4, r15 = row & 15;    // staging row split

    // ===================== Phase G: MFMA GEMM + lower stats ================
    f32x4 acc[4];                                // acc[rg]
#pragma unroll
    for (int rg = 0; rg < 4; ++rg)
#pragma unroll
        for (int r = 0; r < 4; ++r) acc[rg][r] = 0.f;
    float sR = 0.f, qR = 0.f;

    const s16x8* wp = reinterpret_cast<const s16x8*>(whG);
    const s16x8* lp = reinterpret_cast<const s16x8*>(wlG);
    float4 xv[8];
    s16x8 bhC[4], blC[4], bhN[4], blN[4];
    {   // prologue: chunk 0 (x: cols fq*32..+31 of row; B: 4 subchunks)
        const float* rp = x + (size_t)(T0 + row) * C_ + fq * 32;
#pragma unroll
        for (int i = 0; i < 8; ++i) xv[i] = ld4(rp + i * 4);
#pragma unroll
        for (int kk = 0; kk < 4; ++kk) {
            bhC[kk] = wp[(size_t)(kk * 4 + w) * 64 + lane];
            blC[kk] = lp[(size_t)(kk * 4 + w) * 64 + lane];
        }
    }

#pragma unroll 1
    for (int c = 0; c < NCH_; ++c) {
        short* H = S + (c & 1) * 16384;
        short* L = H + 8192;
        // ---- stage 64x128 hi/lo from regs + f32 stats ----
        // thread covers sub-chunk kk=fq, k-in-sub m = i*4+e (i<8,e<4)
        {
            const int base = fq * 2048 + rgS * 512 + r15 * 8;
#pragma unroll
            for (int q = 0; q < 4; ++q) {
                const float xs[8] = {xv[2 * q].x, xv[2 * q].y,
                                     xv[2 * q].z, xv[2 * q].w,
                                     xv[2 * q + 1].x, xv[2 * q + 1].y,
                                     xv[2 * q + 1].z, xv[2 * q + 1].w};
                s16x8 hv, lv;
#pragma unroll
                for (int j = 0; j < 8; ++j) {
                    const unsigned short h = f2bf(xs[j]);
                    hv[j] = (short)h;
                    lv[j] = (short)f2bf(xs[j] - bf2f(h));
                }
                const int sidx = base + q * 128;   // ls = q*16 + r15
                *reinterpret_cast<s16x8*>(H + sidx) = hv;
                *reinterpret_cast<s16x8*>(L + sidx) = lv;
                sR += ((xs[0] + xs[1]) + (xs[2] + xs[3]))
                    + ((xs[4] + xs[5]) + (xs[6] + xs[7]));
#pragma unroll
                for (int j = 0; j < 8; ++j) qR = fmaf(xs[j], xs[j], qR);
            }
        }
        __syncthreads();
        // ---- prefetch chunk c+1 (8 b128 x + 8 b128 B, all in flight) ----
        if (c + 1 < NCH_) {
            const float* rp = x + (size_t)(T0 + row) * C_
                              + (c + 1) * BKC_ + fq * 32;
#pragma unroll
            for (int i = 0; i < 8; ++i) xv[i] = ld4(rp + i * 4);
#pragma unroll
            for (int kk = 0; kk < 4; ++kk) {
                bhN[kk] = wp[(size_t)(((c + 1) * 4 + kk) * 4 + w) * 64 + lane];
                blN[kk] = lp[(size_t)(((c + 1) * 4 + kk) * 4 + w) * 64 + lane];
            }
        }
        // ---- MFMA: 4 kk x 4 rg x 3 products ----
#pragma unroll
        for (int kk = 0; kk < 4; ++kk) {
#pragma unroll
            for (int rg = 0; rg < 4; ++rg) {
                const int ridx = kk * 2048 + rg * 512 + lane * 8;
                const s16x8 Ah = *reinterpret_cast<const s16x8*>(H + ridx);
                const s16x8 Al = *reinterpret_cast<const s16x8*>(L + ridx);
                acc[rg] = __builtin_amdgcn_mfma_f32_16x16x32_bf16(
                    Ah, bhC[kk], acc[rg], 0, 0, 0);
                acc[rg] = __builtin_amdgcn_mfma_f32_16x16x32_bf16(
                    Al, bhC[kk], acc[rg], 0, 0, 0);
                acc[rg] = __builtin_amdgcn_mfma_f32_16x16x32_bf16(
                    Ah, blC[kk], acc[rg], 0, 0, 0);
            }
        }
#pragma unroll
        for (int kk = 0; kk < 4; ++kk) {
            bhC[kk] = bhN[kk];
            blC[kk] = blN[kk];
        }
    }
    // ---- write P: D layout col=lane&15, row=(lane>>4)*4+reg (m89) ----
#pragma unroll
    for (int rg = 0; rg < 4; ++rg)
#pragma unroll
        for (int r = 0; r < 4; ++r) {
            const int tok = T0 + rg * 16 + (lane >> 4) * 4 + r;
            Pp[(size_t)tok * D_ + w * 16 + (lane & 15)] = acc[rg][r];
        }
    // ---- lower-stats reduce over fq (lanes row*4+fq) ----
    sR += __shfl_xor(sR, 1); qR += __shfl_xor(qR, 1);
    sR += __shfl_xor(sR, 2); qR += __shfl_xor(qR, 2);
    if (fq == 0) { sLow[row] = sR; qLow[row] = qR; }
    __syncthreads();

    // ===================== Phase U: upper stats + g-accum ==================
    float4 wv[8], bv[8], gacc[8];
#pragma unroll
    for (int m = 0; m < 8; ++m) {
        wv[m] = ld4(lnw + HC_ + (m * 64 + lane) * 4);
        bv[m] = ld4(lnb + HC_ + (m * 64 + lane) * 4);
        gacc[m] = make_float4(0.f, 0.f, 0.f, 0.f);
    }
    for (int i = 0; i < 16; ++i) {
        const int r = w * 16 + i;
        const int tok = T0 + r;
        const float* rowp = x + (size_t)tok * C_ + HC_;
        float4 v[8];
        float s = 0.f, q = 0.f;
#pragma unroll
        for (int m = 0; m < 8; ++m) {
            v[m] = ld4(rowp + (m * 64 + lane) * 4);
            s += (v[m].x + v[m].y) + (v[m].z + v[m].w);
            q = fmaf(v[m].x, v[m].x, fmaf(v[m].y, v[m].y,
                fmaf(v[m].z, v[m].z, fmaf(v[m].w, v[m].w, q))));
        }
#pragma unroll
        for (int o = 1; o < 64; o <<= 1) {
            s += __shfl_xor(s, o);
            q += __shfl_xor(q, o);
        }
        const float S_ = s + sLow[r];
        const float Q_ = q + qLow[r];
        const float mu = S_ * (1.f / C_);
        const float rs = rsqrtf(Q_ * (1.f / C_) - mu * mu + 1e-5f);
        if (lane == 0) {
            muv[tok] = mu;
            rsv[tok] = rs;
        }
#pragma unroll
        for (int m = 0; m < 8; ++m) {
            gacc[m].x += (v[m].x - mu) * rs * wv[m].x + bv[m].x;
            gacc[m].y += (v[m].y - mu) * rs * wv[m].y + bv[m].y;
            gacc[m].z += (v[m].z - mu) * rs * wv[m].z + bv[m].z;
            gacc[m].w += (v[m].w - mu) * rs * wv[m].w + bv[m].w;
        }
    }
    float (*sh)[HC_] = reinterpret_cast<float(*)[HC_]>(S);
    __syncthreads();   // phase-G LDS dead before overwrite
#pragma unroll
    for (int m = 0; m < 8; ++m)
        *reinterpret_cast<float4*>(&sh[w][(m * 64 + lane) * 4]) = gacc[m];
    __syncthreads();
    float* pp = part + (size_t)tid * HC_;
#pragma unroll
    for (int m = 0; m < 8; ++m) {
        const int j = (m * 64 + lane) * 4;
        const float4 a0 = ld4(&sh[0][j]);
        const float4 a1 = ld4(&sh[1][j]);
        const float4 a2 = ld4(&sh[2][j]);
        const float4 a3 = ld4(&sh[3][j]);
        float4 r;
        r.x = (a0.x + a1.x) + (a2.x + a3.x);
        r.y = (a0.y + a1.y) + (a2.y + a3.y);
        r.z = (a0.z + a1.z) + (a2.z + a3.z);
        r.w = (a0.w + a1.w) + (a2.w + a3.w);
        if (w == (m & 3))
            *reinterpret_cast<float4*>(pp + j) = r;
    }
}

// ---------------------------------------------------------------------------
// K2a: fold partial-reduce + partial GEMVs.  grid 264, block 256.
// ---------------------------------------------------------------------------
__global__ __launch_bounds__(256) void k2a_part(
        const float* __restrict__ part, const float* __restrict__ w1,
        const float* __restrict__ lnw, const float* __restrict__ lnb,
        float* __restrict__ gpart, float* __restrict__ Wpart,
        float* __restrict__ Bpart) {
    __shared__ float Gs[256];
    __shared__ float red[512];
    const int t = threadIdx.x;
    const int d = t & 63, s = t >> 6;
    const int blk = blockIdx.x;
    if (blk < 256) {
        const int b = blk >> 3, jq = blk & 7;
        const int j = jq * 256 + t;
        float a = 0.f;
        for (int k = 0; k < 16; ++k)
            a += part[(size_t)(b * 16 + k) * HC_ + j];
        Gs[t] = a;
        __syncthreads();
        float acc = 0.f;
        const int j0 = jq * 256 + s * 64;
        for (int jj = 0; jj < 64; ++jj)
            acc = fmaf(Gs[s * 64 + jj],
                       w1[(size_t)(HC_ + j0 + jj) * D_ + d], acc);
        red[s * 64 + d] = acc;
        __syncthreads();
        if (s == 0)
            gpart[(size_t)blk * 64 + d] =
                red[d] + red[64 + d] + red[128 + d] + red[192 + d];
    } else {
        const int wq = blk - 256;
        const int c0 = wq * 256 + s * 64;
        float a = 0.f, c2 = 0.f;
        for (int c = c0; c < c0 + 64; ++c) {
            const float wvv = w1[(size_t)c * D_ + d];
            a = fmaf(lnw[c], wvv, a);
            c2 = fmaf(lnb[c], wvv, c2);
        }
        red[s * 64 + d] = a;
        red[256 + s * 64 + d] = c2;
        __syncthreads();
        if (s == 0) {
            Wpart[wq * 64 + d] =
                red[d] + red[64 + d] + red[128 + d] + red[192 + d];
            Bpart[wq * 64 + d] = red[256 + d] + red[320 + d]
                               + red[384 + d] + red[448 + d];
        }
    }
}

// ---------------------------------------------------------------------------
// K45: decision (k2b folded) + masked copy + dz store.  One wave per token.
// ---------------------------------------------------------------------------
__global__ __launch_bounds__(256) void k45_decide_mask(
        const float* __restrict__ Pp, const float* __restrict__ muv,
        const float* __restrict__ rsv, const float* __restrict__ gpart,
        const float* __restrict__ Wpart, const float* __restrict__ Bpart,
        const float* __restrict__ b1, const float* __restrict__ w2,
        const float* __restrict__ b2, const float* __restrict__ gum,
        const float* __restrict__ x, float* __restrict__ out,
        float* __restrict__ dzv) {
    const int t = threadIdx.x;
    const int lane = t & 63, w = t >> 6;
    const int token = blockIdx.x * 4 + w;
    const int b = token >> 10;

    float W1 = 0.f, Bsv = 0.f, gt = 0.f;
#pragma unroll
    for (int q = 0; q < 8; ++q) {
        W1 += Wpart[q * 64 + lane];
        Bsv += Bpart[q * 64 + lane];
        gt += gpart[(size_t)(b * 8 + q) * 64 + lane];
    }
    gt *= (1.f / N_);

    const float2 gv = *reinterpret_cast<const float2*>(gum + token * 2);
    const float p = Pp[(size_t)token * D_ + lane];
    const float mu = muv[token], rs = rsv[token];
    float h = rs * (p - mu * W1) + Bsv + gt + b1[lane];
    h = 0.5f * h * (1.f + erff(h * 0.70710678118654752f));   // exact gelu
    const float2 w2v = *reinterpret_cast<const float2*>(w2 + lane * 2);
    float l0 = h * w2v.x;
    float l1 = h * w2v.y;
#pragma unroll
    for (int o = 1; o < 64; o <<= 1) {
        l0 += __shfl_xor(l0, o);
        l1 += __shfl_xor(l1, o);
    }
    const float z0 = l0 + b2[0] + gv.x;
    const float z1 = l1 + b2[1] + gv.y;
    if (lane == 0) dzv[token] = z0 - z1;

    float4* dst = reinterpret_cast<float4*>(out + (size_t)token * C_);
    if (z0 >= z1) {    // keep (argmax ties -> index 0): copy x
        const float4* src =
            reinterpret_cast<const float4*>(x + (size_t)token * C_);
#pragma unroll
        for (int c = 0; c < 16; ++c)
            dst[c * 64 + lane] = src[c * 64 + lane];
    } else {           // drop: write zeros, skip the x read
        const float4 z = make_float4(0.f, 0.f, 0.f, 0.f);
#pragma unroll
        for (int c = 0; c < 16; ++c)
            dst[c * 64 + lane] = z;
    }
}

// ---------------------------------------------------------------------------
// K6: cleanup — exact f32 recompute for |dz| < TAU_, unrolled x16 (MLP~24).
// ---------------------------------------------------------------------------
__global__ __launch_bounds__(256) void k6_cleanup(
        const float* __restrict__ x, const float* __restrict__ lnw,
        const float* __restrict__ w1, const float* __restrict__ muv,
        const float* __restrict__ rsv, const float* __restrict__ gpart,
        const float* __restrict__ Wpart, const float* __restrict__ Bpart,
        const float* __restrict__ b1, const float* __restrict__ w2,
        const float* __restrict__ b2, const float* __restrict__ gum,
        const float* __restrict__ dzv, float* __restrict__ out) {
    const int t = threadIdx.x;
    const int lane = t & 63, w = t >> 6;
    const int token = blockIdx.x * 4 + w;
    const float dz = dzv[token];
    if (fabsf(dz) >= TAU_) return;    // wave-uniform

    const float* xr = x + (size_t)token * C_;
    float pa[4] = {0.f, 0.f, 0.f, 0.f};
#pragma unroll 1
    for (int k = 0; k < HC_; k += 16) {
        const float4 xk0 = ld4(xr + k), xk1 = ld4(xr + k + 4);
        const float4 xk2 = ld4(xr + k + 8), xk3 = ld4(xr + k + 12);
        const float4 wk0 = ld4(lnw + k), wk1 = ld4(lnw + k + 4);
        const float4 wk2 = ld4(lnw + k + 8), wk3 = ld4(lnw + k + 12);
        float w1v[16];
#pragma unroll
        for (int j = 0; j < 16; ++j)
            w1v[j] = w1[(size_t)(k + j) * D_ + lane];
        const float xs[16] = {xk0.x * wk0.x, xk0.y * wk0.y,
                              xk0.z * wk0.z, xk0.w * wk0.w,
                              xk1.x * wk1.x, xk1.y * wk1.y,
                              xk1.z * wk1.z, xk1.w * wk1.w,
                              xk2.x * wk2.x, xk2.y * wk2.y,
                              xk2.z * wk2.z, xk2.w * wk2.w,
                              xk3.x * wk3.x, xk3.y * wk3.y,
                              xk3.z * wk3.z, xk3.w * wk3.w};
#pragma unroll
        for (int j = 0; j < 16; ++j)
            pa[j & 3] = fmaf(xs[j], w1v[j], pa[j & 3]);
    }
    const float p = (pa[0] + pa[1]) + (pa[2] + pa[3]);

    const int b = token >> 10;
    float W1 = 0.f, Bsv = 0.f, gt = 0.f;
#pragma unroll
    for (int q = 0; q < 8; ++q) {
        W1 += Wpart[q * 64 + lane];
        Bsv += Bpart[q * 64 + lane];
        gt += gpart[(size_t)(b * 8 + q) * 64 + lane];
    }
    gt *= (1.f / N_);
    const float2 gv = *reinterpret_cast<const float2*>(gum + token * 2);
    const float mu = muv[token], rs = rsv[token];
    float h = rs * (p - mu * W1) + Bsv + gt + b1[lane];
    h = 0.5f * h * (1.f + erff(h * 0.70710678118654752f));
    const float2 w2v = *reinterpret_cast<const float2*>(w2 + lane * 2);
    float l0 = h * w2v.x;
    float l1 = h * w2v.y;
#pragma unroll
    for (int o = 1; o < 64; o <<= 1) {
        l0 += __shfl_xor(l0, o);
        l1 += __shfl_xor(l1, o);
    }
    const float z0 = l0 + b2[0] + gv.x;
    const float z1 = l1 + b2[1] + gv.y;
    const bool keepNew = (z0 >= z1);
    const bool keepOld = (dz >= 0.f);
    if (keepNew == keepOld) return;

    float4* dst = reinterpret_cast<float4*>(out + (size_t)token * C_);
    if (keepNew) {
        const float4* src = reinterpret_cast<const float4*>(xr);
#pragma unroll
        for (int c = 0; c < 16; ++c)
            dst[c * 64 + lane] = src[c * 64 + lane];
    } else {
        const float4 z = make_float4(0.f, 0.f, 0.f, 0.f);
#pragma unroll
        for (int c = 0; c < 16; ++c)
            dst[c * 64 + lane] = z;
    }
}

// ---------------------------------------------------------------------------
extern "C" void kernel_launch(void* const* d_in, const int* in_sizes, int n_in,
                              void* d_out, int out_size, void* d_ws,
                              size_t ws_size, hipStream_t stream) {
    const float* x   = (const float*)d_in[0];
    const float* gum = (const float*)d_in[1];
    const float* lnw = (const float*)d_in[2];
    const float* lnb = (const float*)d_in[3];
    const float* w1  = (const float*)d_in[4];
    const float* b1  = (const float*)d_in[5];
    const float* w2  = (const float*)d_in[6];
    const float* b2  = (const float*)d_in[7];
    float* out = (float*)d_out;

    float* wsf   = (float*)d_ws;
    float* Pp    = wsf;                                   // 32768*64
    float* muv   = Pp + (size_t)NT_ * D_;                 // 32768
    float* rsv   = muv + NT_;                             // 32768
    float* part  = rsv + NT_;                             // 512*2048
    float* gpart = part + (size_t)512 * HC_;              // 256*64
    float* Wpart = gpart + 256 * 64;                      // 8*64
    float* Bpart = Wpart + 8 * 64;                        // 8*64
    float* dzv   = Bpart + 8 * 64;                        // 32768
    short* whG   = (short*)(dzv + NT_);                   // 131072 shorts
    short* wlG   = whG + (size_t)131072;                  // 131072 shorts

    k0_prep<<<256, 64, 0, stream>>>(lnw, w1, whG, wlG);
    mk1m<<<512, 256, 0, stream>>>(x, lnw, lnb, whG, wlG, Pp, muv, rsv, part);
    k2a_part<<<264, 256, 0, stream>>>(part, w1, lnw, lnb,
                                      gpart, Wpart, Bpart);
    k45_decide_mask<<<NT_ / 4, 256, 0, stream>>>(Pp, muv, rsv, gpart,
                                                 Wpart, Bpart, b1, w2, b2,
                                                 gum, x, out, dzv);
    k6_cleanup<<<NT_ / 4, 256, 0, stream>>>(x, lnw, w1, muv, rsv, gpart,
                                            Wpart, Bpart, b1, w2, b2,
                                            gum, dzv, out);
}